// Round 10
// baseline (395.109 us; speedup 1.0000x reference)
//
#include <hip/hip_runtime.h>
#include <hip/hip_fp8.h>
#include <stdint.h>

// Problem constants (fixed by reference setup_inputs)
constexpr int N    = 8192;
constexpr int D    = 512;
constexpr int KEXT = 8;
constexpr int NCLS = 1000;
#define TAU_INV  14.285714285714285714f   // 1/0.07
// sqrt(log2(e)/tau) folded into packed fp8: acc = (q_i . q_j)/tau * log2(e),
// so the epilogue uses a single v_exp_f32 (exp2) per element.
#define SC_L2    4.539816423767765f

typedef long   long2_t __attribute__((ext_vector_type(2)));  // 16B half-fragment (4 VGPR)
typedef float  f32x16  __attribute__((ext_vector_type(16))); // 32x32 C/D fragment
typedef int    v8i     __attribute__((ext_vector_type(8)));  // 32B MX fp8 operand

typedef __attribute__((address_space(1))) void gvoid;
typedef __attribute__((address_space(3))) void lvoid;

__device__ __forceinline__ uint32_t pack4_e4m3(float a, float b, float c, float d) {
    __hip_fp8_e4m3 A(a), B(b), C(c), D(d);   // OCP e4m3fn on gfx950
    return (uint32_t)A.__x | ((uint32_t)B.__x << 8) |
           ((uint32_t)C.__x << 16) | ((uint32_t)D.__x << 24);
}

// MX-scaled 32x32x64 fp8 MFMA, unit scales (e8m0 127 -> 2^0): numerically a
// plain e4m3 matmul at the 2x MX rate. Operand layout: lane = kblock*32+row
// (row=lane&31 for A / col for B), each lane 32 contiguous k-bytes.
__device__ __forceinline__ f32x16 mfma32(long2_t alo, long2_t ahi,
                                         long2_t blo, long2_t bhi, f32x16 c) {
    union U { long2_t h[2]; v8i v; } A, B;
    A.h[0] = alo; A.h[1] = ahi;
    B.h[0] = blo; B.h[1] = bhi;
    return __builtin_amdgcn_mfma_scale_f32_32x32x64_f8f6f4(
        A.v, B.v, c, 0, 0, 0, 127, 0, 127);
}

// ---------------- fused prep: histogram + fp8 fragment-packing of q --------
// qf8 layout for mfma_scale 32x32x64: fragment = (t32 = 32-row tile,
// ks2 = 64-wide K step). Lane l supplies row t32*32+(l&31), k-bytes
// ks2*64 + (l>>5)*32 .. +32, stored as two 16B planes (lane-stride 16B =
// the proven conflict-free pattern):
//   16B slot (t32*8+ks2)*128 +      l : lane's k-bytes [0..16)
//   16B slot (t32*8+ks2)*128 + 64 + l : lane's k-bytes [16..32)
// A 128-row band (4 tiles) is a CONTIGUOUS 64KB region -> linear LDS DMA.
// Also emits invy[j] = 1/count[y[j]].
__global__ void prep_k(const float* __restrict__ q, const int* __restrict__ y,
                       uint32_t* __restrict__ qf8, int* __restrict__ counts,
                       float* __restrict__ invy, float* __restrict__ pos,
                       float* __restrict__ neg) {
    const int b = blockIdx.x, tid = threadIdx.x;
    if (b == 0) {
        __shared__ int h[NCLS];
        for (int i = tid; i < NCLS; i += 256) h[i] = 0;
        __syncthreads();
        for (int i = tid; i < N; i += 256) atomicAdd(&h[y[i]], 1);
        __syncthreads();
        for (int i = tid; i < NCLS; i += 256) counts[i] = h[i];
        for (int i = tid; i < N; i += 256) invy[i] = 1.0f / (float)h[y[i]];
        return;
    }
    const int gid  = (b - 1) * 256 + tid;    // over N*16 granules of 32B
    const int grp  = gid >> 6;               // (t32,ks2) fragment 0..2047
    const int lane = gid & 63;
    const int row  = (grp >> 3) * 32 + (lane & 31);
    const int k0   = (grp & 7) * 64 + (lane >> 5) * 32;
    const float* src = q + (size_t)row * D + k0;
    uint32_t o[8];
#pragma unroll
    for (int j = 0; j < 8; j++) {
        float4 v = *reinterpret_cast<const float4*>(src + j * 4);
        o[j] = pack4_e4m3(v.x * SC_L2, v.y * SC_L2, v.z * SC_L2, v.w * SC_L2);
    }
    uint4* dst = reinterpret_cast<uint4*>(qf8);
    const size_t s16 = (size_t)grp * 128 + lane;
    dst[s16]      = make_uint4(o[0], o[1], o[2], o[3]);   // plane0: k 0..15
    dst[s16 + 64] = make_uint4(o[4], o[5], o[6], o[7]);   // plane1: k 16..31
    if (gid < N) { pos[gid] = 0.f; neg[gid] = 0.f; }
}

// ---------------- band-sweep GEMM (q @ q^T) + fused contrastive epilogue ---
// 512 blocks = 64 row-bands x 8 col-chunks of 1024; 256 threads, 2x2 waves,
// 64x64 wave tile = 2x2 fragments of 32x32x64 MX MFMA. The shape change is
// the register fix (R1..R9 ablation): 16x16x128 needed A 32 + B-dbuf 64
// arch VGPRs for fragments alone -> arch demand ~220 > 192 available
// (accum_offset 192 / acc 64 AGPR) -> every variant spilled 40-300MB.
// 32x32x64 halves fragment count: A 16 + B-dbuf 32; arch demand ~165 < 192.
// Schedule keeps all R1 guards: explicit B register double-buffer,
// cross-jt pre-issue, compiler-unrolled jt loop, register row-sums.
__global__ __launch_bounds__(256, 2) void gemm_k(
        const uint32_t* __restrict__ qf8,
        const int* __restrict__ y,
        const float* __restrict__ invy,
        float* __restrict__ pos_sum,
        float* __restrict__ neg_sum) {
    __shared__ long2_t Asl[4096];       // 64KB: band's 4 tiles x 8 ks2 x 2 planes
    __shared__ int   yR[128];           // band labels
    __shared__ float redP[2][128];      // column-half partials
    __shared__ float redN[2][128];

    const int tid  = threadIdx.x;
    const int wave = tid >> 6;
    const int lane = tid & 63;
    const int l31  = lane & 31;
    const int hi   = lane >> 5;

    const int ib     = blockIdx.x >> 3;       // row band 0..63
    const int jchunk = blockIdx.x & 7;        // 1024-col chunk
    const int ibase  = ib * 128;

    // ---- DMA A-band into LDS: pure linear 64KB copy ----
    {
        const uint32_t* src = qf8 + (size_t)ib * 16384;   // 4096 x 16B
#pragma unroll
        for (int it = 0; it < 16; it++) {
            const int idx = it * 256 + tid;
            __builtin_amdgcn_global_load_lds((gvoid*)(src + idx * 4),
                                             (lvoid*)(Asl + idx), 16, 0, 0);
        }
    }
    if (tid < 128) yR[tid] = y[ibase + tid];
    __syncthreads();   // DMA drained (compiler emits vmcnt(0) before barrier)

    // wave position: 2x2 waves over each 128x128 subtile
    const int wr   = (wave >> 1) * 64;
    const int wc   = (wave & 1) * 64;
    const int colh = wave & 1;
    const int tA   = wr >> 5;                // local A tile base (0 or 2)

    // per-lane row labels for this lane's 32 output rows, packed 2xu16
    // (row_local(r) = (r&3) + 8*(r>>2) + 4*hi within each 32-row fragment)
    uint32_t yiP[16];
#pragma unroll
    for (int mi = 0; mi < 2; mi++)
#pragma unroll
        for (int rr = 0; rr < 8; rr++) {
            const int r0 = 2 * rr, r1 = 2 * rr + 1;
            const int il0 = wr + mi * 32 + (r0 & 3) + 8 * (r0 >> 2) + 4 * hi;
            const int il1 = wr + mi * 32 + (r1 & 3) + 8 * (r1 >> 2) + 4 * hi;
            yiP[mi * 8 + rr] = (uint32_t)yR[il0] | ((uint32_t)yR[il1] << 16);
        }

    float posp[32], negp[32];
#pragma unroll
    for (int e = 0; e < 32; e++) { posp[e] = 0.f; negp[e] = 0.f; }

    const long2_t* fbL = reinterpret_cast<const long2_t*>(qf8);
    // B fragment base pointers (16B units): col-tile ct = jchunk*32+(wc>>5)+mj
    const long2_t* pB[2];
#pragma unroll
    for (int m = 0; m < 2; m++)
        pB[m] = fbL + (size_t)(jchunk * 32 + (wc >> 5) + m) * 1024 + lane;

    // B double-buffer registers; prologue for jt=0
    long2_t blo[2][2], bhi[2][2];
#pragma unroll
    for (int m = 0; m < 2; m++) {
        blo[0][m] = pB[m][0];
        bhi[0][m] = pB[m][64];
    }

    for (int jt = 0; jt < 8; jt++) {
        const int j0 = jchunk * 1024 + jt * 128;

        // column metadata: col = j0 + wc + mj*32 + l31 (fixed per lane)
        int   yjv[2];
        float icj[2];
#pragma unroll
        for (int mj = 0; mj < 2; mj++) {
            const int jc = j0 + wc + mj * 32 + l31;
            yjv[mj] = y[jc];
            icj[mj] = invy[jc];
        }

        f32x16 acc[2][2];
#pragma unroll
        for (int a = 0; a < 2; a++)
#pragma unroll
            for (int c = 0; c < 2; c++) acc[a][c] = (f32x16)0.0f;

        // K-loop: 8 macro-steps of K=64; B register double-buffered. On the
        // last step, pre-issue NEXT jt's first fragments (slot is free) so
        // they stay in flight across the epilogue.
#pragma unroll
        for (int ks2 = 0; ks2 < 8; ks2++) {
            const int cur = ks2 & 1, nxt = cur ^ 1;
            if (ks2 < 7) {
#pragma unroll
                for (int m = 0; m < 2; m++) {
                    blo[nxt][m] = pB[m][(ks2 + 1) * 128];
                    bhi[nxt][m] = pB[m][(ks2 + 1) * 128 + 64];
                }
            } else if (jt < 7) {
#pragma unroll
                for (int m = 0; m < 2; m++) {
                    blo[nxt][m] = pB[m][4096];        // next 128 cols, ks2=0
                    bhi[nxt][m] = pB[m][4096 + 64];
                }
            }
            long2_t alo[2], ahi[2];
#pragma unroll
            for (int m = 0; m < 2; m++) {
                alo[m] = Asl[((tA + m) * 8 + ks2) * 128 + lane];
                ahi[m] = Asl[((tA + m) * 8 + ks2) * 128 + 64 + lane];
            }
#pragma unroll
            for (int mi = 0; mi < 2; mi++)
#pragma unroll
                for (int mj = 0; mj < 2; mj++)
                    acc[mi][mj] = mfma32(alo[mi], ahi[mi],
                                         blo[cur][mj], bhi[cur][mj],
                                         acc[mi][mj]);
        }
#pragma unroll
        for (int m = 0; m < 2; m++) pB[m] += 4096;   // next 128 cols (4 tiles)

        // fused epilogue: acc holds sim/tau*log2e. C/D: col=lane&31,
        // row=(r&3)+8*(r>>2)+4*hi. Register row-sums across jt (R1 pattern).
#pragma unroll
        for (int mi = 0; mi < 2; mi++) {
#pragma unroll
            for (int r = 0; r < 16; r++) {
                const int il   = wr + mi * 32 + (r & 3) + 8 * (r >> 2) + 4 * hi;
                const int irow = ibase + il;
                const uint32_t p = yiP[mi * 8 + (r >> 1)];
                const int myi = (int)((r & 1) ? (p >> 16) : (p & 0xffffu));
                float ps = 0.f, ns = 0.f;
#pragma unroll
                for (int mj = 0; mj < 2; mj++) {
                    const int jcol = j0 + wc + mj * 32 + l31;
                    float a    = acc[mi][mj][r];
                    float ex   = __builtin_amdgcn_exp2f(a);     // exp(sim/tau)
                    bool  nz   = (a != 0.0f);                   // faithful masked_fill(x==0,-inf)
                    bool  same = (myi == yjv[mj]);
                    ps += (same && (irow != jcol) && nz) ? ex : 0.0f;
                    ns += (!same && nz) ? ex * icj[mj] : 0.0f;
                }
                posp[mi * 16 + r] += ps;
                negp[mi * 16 + r] += ns;
            }
        }
    }

    // ---- commit: 32-lane reduce (within wave half) -> LDS -> 256 atomics ----
#pragma unroll
    for (int mi = 0; mi < 2; mi++) {
#pragma unroll
        for (int r = 0; r < 16; r++) {
            float ps = posp[mi * 16 + r], ns = negp[mi * 16 + r];
#pragma unroll
            for (int off = 1; off < 32; off <<= 1) {
                ps += __shfl_xor(ps, off);
                ns += __shfl_xor(ns, off);
            }
            if (l31 == 0) {   // lanes 0 (hi=0) and 32 (hi=1) write their rows
                const int il = wr + mi * 32 + (r & 3) + 8 * (r >> 2) + 4 * hi;
                redP[colh][il] = ps;
                redN[colh][il] = ns;
            }
        }
    }
    __syncthreads();
    if (tid < 128) {
        atomicAdd(&pos_sum[ibase + tid], redP[0][tid] + redP[1][tid]);
    } else if (tid < 256) {
        const int il = tid - 128;
        atomicAdd(&neg_sum[ibase + il], redN[0][il] + redN[1][il]);
    }
}

// ---------------- per-row finalize: k_sims (fp32, float4 loads) ------------
__global__ void finalize_k(const float* __restrict__ q, const float* __restrict__ kmat,
                           const int* __restrict__ y, const int* __restrict__ counts,
                           const float* __restrict__ pos_sum, const float* __restrict__ neg_sum,
                           float* __restrict__ loss) {
    const int wave = threadIdx.x >> 6, lane = threadIdx.x & 63;
    const int i = blockIdx.x * 4 + wave;

    const float4* q4 = reinterpret_cast<const float4*>(q) + (size_t)i * 128;
    const float4* k4 = reinterpret_cast<const float4*>(kmat) + (size_t)i * KEXT * 128;
    float4 qa = q4[lane], qb = q4[lane + 64];

    float esum = 0.f;
    for (int kk = 0; kk < KEXT; kk++) {
        float4 ka = k4[(size_t)kk * 128 + lane];
        float4 kb = k4[(size_t)kk * 128 + lane + 64];
        float p = qa.x * ka.x;
        p = fmaf(qa.y, ka.y, p); p = fmaf(qa.z, ka.z, p); p = fmaf(qa.w, ka.w, p);
        p = fmaf(qb.x, kb.x, p); p = fmaf(qb.y, kb.y, p);
        p = fmaf(qb.z, kb.z, p); p = fmaf(qb.w, kb.w, p);
#pragma unroll
        for (int off = 1; off < 64; off <<= 1) p += __shfl_xor(p, off);
        esum += __expf(p * TAU_INV);
    }
    if (lane == 0) {
        float num = logf(esum + pos_sum[i]);
        float den = logf(neg_sum[i]);
        float cnt = (float)(counts[y[i]] - 1 + KEXT);  // same_class_counts, label-only
        loss[i] = -(num - den) / cnt;
    }
}

__global__ void reduce_k(const float* __restrict__ loss, float* __restrict__ out) {
    __shared__ float part[16];
    int tid = threadIdx.x;   // 1024 threads
    float s = 0.f;
    for (int i = tid; i < N; i += 1024) s += loss[i];
#pragma unroll
    for (int off = 1; off < 64; off <<= 1) s += __shfl_xor(s, off);
    if ((tid & 63) == 0) part[tid >> 6] = s;
    __syncthreads();
    if (tid < 16) {
        float v = part[tid];
#pragma unroll
        for (int off = 1; off < 16; off <<= 1) v += __shfl_xor(v, off);
        if (tid == 0) out[0] = v / (float)N;
    }
}

// ---------------- launch ----------------
extern "C" void kernel_launch(void* const* d_in, const int* in_sizes, int n_in,
                              void* d_out, int out_size, void* d_ws, size_t ws_size,
                              hipStream_t stream) {
    const float* q    = (const float*)d_in[0];
    const float* kmat = (const float*)d_in[1];
    const int*   y    = (const int*)d_in[2];
    float* out = (float*)d_out;

    char* ws = (char*)d_ws;
    uint32_t* qf8  = (uint32_t*)ws;                 // 4 MB: packed fp8 fragments
    int*   counts  = (int*)  (ws + 4194304);        // 1000 ints
    float* invy    = (float*)(ws + 4198400);        // N floats: 1/count[y[j]]
    float* pos     = (float*)(ws + 4231168);        // N floats
    float* neg     = (float*)(ws + 4263936);        // N floats
    float* loss    = (float*)(ws + 4296704);        // N floats

    prep_k    <<<1 + (N * 16) / 256, 256, 0, stream>>>(q, y, qf8, counts, invy, pos, neg);
    gemm_k    <<<512, 256, 0, stream>>>(qf8, y, invy, pos, neg);
    finalize_k<<<N / 4, 256, 0, stream>>>(q, kmat, y, counts, pos, neg, loss);
    reduce_k  <<<1, 1024, 0, stream>>>(loss, out);
}

// Round 11
// 289.516 us; speedup vs baseline: 1.3647x; 1.3647x over previous
//
#include <hip/hip_runtime.h>
#include <hip/hip_fp8.h>
#include <stdint.h>

// Problem constants (fixed by reference setup_inputs)
constexpr int N    = 8192;
constexpr int D    = 512;
constexpr int KEXT = 8;
constexpr int NCLS = 1000;
#define TAU_INV  14.285714285714285714f   // 1/0.07
// sqrt(log2(e)/tau) folded into packed fp8: acc = (q_i . q_j)/tau * log2(e),
// so the epilogue uses a single v_exp_f32 (exp2) per element.
#define SC_L2    4.539816423767765f

typedef long   long2_t __attribute__((ext_vector_type(2)));  // 16B half-fragment
typedef float  f32x4   __attribute__((ext_vector_type(4)));
typedef int    v8i     __attribute__((ext_vector_type(8)));  // 32B MX fp8 operand

typedef __attribute__((address_space(1))) void gvoid;
typedef __attribute__((address_space(3))) void lvoid;

__device__ __forceinline__ uint32_t pack4_e4m3(float a, float b, float c, float d) {
    __hip_fp8_e4m3 A(a), B(b), C(c), D(d);   // OCP e4m3fn on gfx950
    return (uint32_t)A.__x | ((uint32_t)B.__x << 8) |
           ((uint32_t)C.__x << 16) | ((uint32_t)D.__x << 24);
}

// MX-scaled fp8 MFMA, unit scales (e8m0 127 -> 2^0): bit-identical to plain
// e4m3 matmul but at the 2x MX rate (K=128/instr). cbsz=0/blgp=0 = fp8 e4m3.
__device__ __forceinline__ f32x4 mfma128(long2_t alo, long2_t ahi,
                                         long2_t blo, long2_t bhi, f32x4 c) {
    union U { long2_t h[2]; v8i v; } A, B;
    A.h[0] = alo; A.h[1] = ahi;
    B.h[0] = blo; B.h[1] = bhi;
    return __builtin_amdgcn_mfma_scale_f32_16x16x128_f8f6f4(
        A.v, B.v, c, 0, 0, 0, 127, 0, 127);
}

// ---------------- fused prep: histogram + fp8 fragment-packing of q --------
// qf8 layout for mfma_scale 16x16x128 (lane = quad*16+l15 supplies row=l15's
// 32 CONTIGUOUS k-bytes at k = quad*32): per (tile t, kstep ks4) a 2KB block
// split in two 16B-stride planes so ds_read_b128 stays bank-conflict-free:
//   16B slot (t*4+ks4)*128 +      lane  = bytes k[0..16)   of lane's block
//   16B slot (t*4+ks4)*128 + 64 + lane  = bytes k[16..32)
// A 128-row band (8 tiles) is a CONTIGUOUS 64KB region -> linear LDS DMA.
// Also emits invy[j] = 1/count[y[j]] for direct column gathers.
__global__ void prep_k(const float* __restrict__ q, const int* __restrict__ y,
                       uint32_t* __restrict__ qf8, int* __restrict__ counts,
                       float* __restrict__ invy, float* __restrict__ pos,
                       float* __restrict__ neg) {
    const int b = blockIdx.x, tid = threadIdx.x;
    if (b == 0) {
        __shared__ int h[NCLS];
        for (int i = tid; i < NCLS; i += 256) h[i] = 0;
        __syncthreads();
        for (int i = tid; i < N; i += 256) atomicAdd(&h[y[i]], 1);
        __syncthreads();
        for (int i = tid; i < NCLS; i += 256) counts[i] = h[i];
        for (int i = tid; i < N; i += 256) invy[i] = 1.0f / (float)h[y[i]];
        return;
    }
    const int gid = (b - 1) * 256 + tid;     // over N*16 granules of 32B
    const int row = gid >> 4;                // source row of q
    const int kb  = gid & 15;                // 32-elem K block within row
    const int ks4 = kb >> 2, quad = kb & 3;
    const float* src = q + (size_t)row * D + kb * 32;
    uint32_t o[8];
#pragma unroll
    for (int j = 0; j < 8; j++) {
        float4 v = *reinterpret_cast<const float4*>(src + j * 4);
        o[j] = pack4_e4m3(v.x * SC_L2, v.y * SC_L2, v.z * SC_L2, v.w * SC_L2);
    }
    const int t = row >> 4, l15 = row & 15;
    const size_t s16 = (size_t)((t * 4 + ks4) * 128) + quad * 16 + l15;
    uint4* dst = reinterpret_cast<uint4*>(qf8);
    dst[s16]      = make_uint4(o[0], o[1], o[2], o[3]);   // lo plane: k 0..15
    dst[s16 + 64] = make_uint4(o[4], o[5], o[6], o[7]);   // hi plane: k 16..31
    if (gid < N) { pos[gid] = 0.f; neg[gid] = 0.f; }
}

// ---------------- band-sweep GEMM (q @ q^T) + fused contrastive epilogue ---
// EXACTLY the R1 98us kernel with ONE change: __launch_bounds__(256, 1).
// R0..R10 post-mortems: at min-2-waves/SIMD the unified 256-reg cap splits
// 128 arch / 128 AGPR (VGPR_Count always = cap/2), and every variant's arch
// live set exceeded 128 -> 40-300MB scratch thrash (WRITE_SIZE) in ALL runs.
// (256,1) raises the budget to 512: R1's full demand (~220 arch + 64 acc)
// fits with slack -> spill impossible. Cost: 1 wave/SIMD occupancy; serial
// arithmetic (MFMA 14.7us floor, B prefetched a full ks-step ahead, epilogue
// ~500cyc/jt) predicts ~45-75us -- still well under the spill-bound 98us.
__global__ __launch_bounds__(256, 1) void gemm_k(
        const uint32_t* __restrict__ qf8,
        const int* __restrict__ y,
        const float* __restrict__ invy,
        float* __restrict__ pos_sum,
        float* __restrict__ neg_sum) {
    __shared__ long2_t Asl[4096];       // 64KB: band's 8 tiles x 4 ks4 x 2 planes
    __shared__ int   yR[128];           // band labels
    __shared__ float redP[2][128];      // column-half partials
    __shared__ float redN[2][128];

    const int tid  = threadIdx.x;
    const int wave = tid >> 6;
    const int lane = tid & 63;
    const int quad = lane >> 4;
    const int l15  = lane & 15;

    const int ib     = blockIdx.x >> 3;       // row band 0..63
    const int jchunk = blockIdx.x & 7;        // 1024-col chunk
    const int ibase  = ib * 128;

    // ---- DMA A-band into LDS: pure linear 64KB copy ----
    {
        const uint32_t* src = qf8 + (size_t)ib * 16384;   // 4096 x 16B
#pragma unroll
        for (int it = 0; it < 16; it++) {
            const int idx = it * 256 + tid;
            __builtin_amdgcn_global_load_lds((gvoid*)(src + idx * 4),
                                             (lvoid*)(Asl + idx), 16, 0, 0);
        }
    }
    if (tid < 128) yR[tid] = y[ibase + tid];
    __syncthreads();   // DMA drained (compiler emits vmcnt(0) before barrier)

    // wave position: 2x2 waves over each 128x128 subtile
    const int wr = (wave >> 1) * 64;
    const int wc = (wave & 1) * 64;
    const int half = wave & 1;

    // per-lane row metadata and register row-sums
    int yi[16];
#pragma unroll
    for (int mi = 0; mi < 4; mi++)
#pragma unroll
        for (int r = 0; r < 4; r++)
            yi[mi * 4 + r] = yR[wr + mi * 16 + quad * 4 + r];

    float posp[16], negp[16];
#pragma unroll
    for (int e = 0; e < 16; e++) { posp[e] = 0.f; negp[e] = 0.f; }

    const long2_t* fbL = reinterpret_cast<const long2_t*>(qf8);
    // B fragment base pointers (16B units) for subtile 0 of this chunk
    const long2_t* pB[4];
#pragma unroll
    for (int m = 0; m < 4; m++)
        pB[m] = fbL + (size_t)(jchunk * 64 + (wc >> 4) + m) * 512 + lane;

    const int tA = wr >> 4;                  // local A tile base (0 or 4)

    // B double-buffer registers; prologue for jt=0
    long2_t blo[2][4], bhi[2][4];
#pragma unroll
    for (int m = 0; m < 4; m++) {
        blo[0][m] = pB[m][0];
        bhi[0][m] = pB[m][64];
    }

    for (int jt = 0; jt < 8; jt++) {
        const int j0 = jchunk * 1024 + jt * 128;

        // column metadata (consumed only in epilogue; latency hidden by K-loop)
        int   yjv[4];
        float icj[4];
#pragma unroll
        for (int mj = 0; mj < 4; mj++) {
            int jc = j0 + wc + mj * 16 + l15;
            yjv[mj] = y[jc];
            icj[mj] = invy[jc];
        }

        f32x4 acc[4][4];
#pragma unroll
        for (int a = 0; a < 4; a++)
#pragma unroll
            for (int c = 0; c < 4; c++) acc[a][c] = (f32x4)0.0f;

        // K-loop: 4 macro-steps of K=128; B register double-buffered. On the
        // last step, pre-issue NEXT jt's first fragments (slot 0 is free) so
        // they stay in flight across the epilogue.
#pragma unroll
        for (int ks4 = 0; ks4 < 4; ks4++) {
            const int cur = ks4 & 1, nxt = cur ^ 1;
            if (ks4 < 3) {
#pragma unroll
                for (int m = 0; m < 4; m++) {
                    blo[nxt][m] = pB[m][(ks4 + 1) * 128];
                    bhi[nxt][m] = pB[m][(ks4 + 1) * 128 + 64];
                }
            } else if (jt < 7) {
#pragma unroll
                for (int m = 0; m < 4; m++) {
                    blo[nxt][m] = pB[m][4096];        // next 128 cols, ks4=0
                    bhi[nxt][m] = pB[m][4096 + 64];
                }
            }
            long2_t alo[4], ahi[4];
#pragma unroll
            for (int m = 0; m < 4; m++) {
                alo[m] = Asl[((tA + m) * 4 + ks4) * 128 + lane];
                ahi[m] = Asl[((tA + m) * 4 + ks4) * 128 + 64 + lane];
            }
#pragma unroll
            for (int mi = 0; mi < 4; mi++)
#pragma unroll
                for (int mj = 0; mj < 4; mj++)
                    acc[mi][mj] = mfma128(alo[mi], ahi[mi],
                                          blo[cur][mj], bhi[cur][mj],
                                          acc[mi][mj]);
        }
#pragma unroll
        for (int m = 0; m < 4; m++) pB[m] += 4096;   // next 128 cols (8 tiles)

        // fused epilogue: acc holds sim/tau*log2e (scale folded into qf8)
#pragma unroll
        for (int mi = 0; mi < 4; mi++) {
#pragma unroll
            for (int r = 0; r < 4; r++) {
                const int e    = mi * 4 + r;
                const int irow = ibase + wr + mi * 16 + quad * 4 + r;
                const int myi  = yi[e];
                float ps = 0.f, ns = 0.f;
#pragma unroll
                for (int mj = 0; mj < 4; mj++) {
                    const int jcol = j0 + wc + mj * 16 + l15;   // C/D: col = lane&15
                    float a    = acc[mi][mj][r];
                    float ex   = __builtin_amdgcn_exp2f(a);     // exp(sim/tau)
                    bool  nz   = (a != 0.0f);                   // faithful masked_fill(x==0,-inf)
                    bool  same = (myi == yjv[mj]);
                    ps += (same && (irow != jcol) && nz) ? ex : 0.0f;
                    ns += (!same && nz) ? ex * icj[mj] : 0.0f;
                }
                posp[e] += ps;
                negp[e] += ns;
            }
        }
    }

    // ---- commit: 16-lane reduce -> LDS column-half combine -> 256 atomics ----
#pragma unroll
    for (int mi = 0; mi < 4; mi++) {
#pragma unroll
        for (int r = 0; r < 4; r++) {
            const int e = mi * 4 + r;
            float ps = posp[e], ns = negp[e];
#pragma unroll
            for (int off = 1; off < 16; off <<= 1) {
                ps += __shfl_xor(ps, off);
                ns += __shfl_xor(ns, off);
            }
            if (l15 == 0) {
                const int il = wr + mi * 16 + quad * 4 + r;
                redP[half][il] = ps;
                redN[half][il] = ns;
            }
        }
    }
    __syncthreads();
    if (tid < 128) {
        atomicAdd(&pos_sum[ibase + tid], redP[0][tid] + redP[1][tid]);
    } else if (tid < 256) {
        const int il = tid - 128;
        atomicAdd(&neg_sum[ibase + il], redN[0][il] + redN[1][il]);
    }
}

// ---------------- per-row finalize: k_sims (fp32, float4 loads) ------------
__global__ void finalize_k(const float* __restrict__ q, const float* __restrict__ kmat,
                           const int* __restrict__ y, const int* __restrict__ counts,
                           const float* __restrict__ pos_sum, const float* __restrict__ neg_sum,
                           float* __restrict__ loss) {
    const int wave = threadIdx.x >> 6, lane = threadIdx.x & 63;
    const int i = blockIdx.x * 4 + wave;

    const float4* q4 = reinterpret_cast<const float4*>(q) + (size_t)i * 128;
    const float4* k4 = reinterpret_cast<const float4*>(kmat) + (size_t)i * KEXT * 128;
    float4 qa = q4[lane], qb = q4[lane + 64];

    float esum = 0.f;
    for (int kk = 0; kk < KEXT; kk++) {
        float4 ka = k4[(size_t)kk * 128 + lane];
        float4 kb = k4[(size_t)kk * 128 + lane + 64];
        float p = qa.x * ka.x;
        p = fmaf(qa.y, ka.y, p); p = fmaf(qa.z, ka.z, p); p = fmaf(qa.w, ka.w, p);
        p = fmaf(qb.x, kb.x, p); p = fmaf(qb.y, kb.y, p);
        p = fmaf(qb.z, kb.z, p); p = fmaf(qb.w, kb.w, p);
#pragma unroll
        for (int off = 1; off < 64; off <<= 1) p += __shfl_xor(p, off);
        esum += __expf(p * TAU_INV);
    }
    if (lane == 0) {
        float num = logf(esum + pos_sum[i]);
        float den = logf(neg_sum[i]);
        float cnt = (float)(counts[y[i]] - 1 + KEXT);  // same_class_counts, label-only
        loss[i] = -(num - den) / cnt;
    }
}

__global__ void reduce_k(const float* __restrict__ loss, float* __restrict__ out) {
    __shared__ float part[16];
    int tid = threadIdx.x;   // 1024 threads
    float s = 0.f;
    for (int i = tid; i < N; i += 1024) s += loss[i];
#pragma unroll
    for (int off = 1; off < 64; off <<= 1) s += __shfl_xor(s, off);
    if ((tid & 63) == 0) part[tid >> 6] = s;
    __syncthreads();
    if (tid < 16) {
        float v = part[tid];
#pragma unroll
        for (int off = 1; off < 16; off <<= 1) v += __shfl_xor(v, off);
        if (tid == 0) out[0] = v / (float)N;
    }
}

// ---------------- launch ----------------
extern "C" void kernel_launch(void* const* d_in, const int* in_sizes, int n_in,
                              void* d_out, int out_size, void* d_ws, size_t ws_size,
                              hipStream_t stream) {
    const float* q    = (const float*)d_in[0];
    const float* kmat = (const float*)d_in[1];
    const int*   y    = (const int*)d_in[2];
    float* out = (float*)d_out;

    char* ws = (char*)d_ws;
    uint32_t* qf8  = (uint32_t*)ws;                 // 4 MB: packed fp8 fragments
    int*   counts  = (int*)  (ws + 4194304);        // 1000 ints
    float* invy    = (float*)(ws + 4198400);        // N floats: 1/count[y[j]]
    float* pos     = (float*)(ws + 4231168);        // N floats
    float* neg     = (float*)(ws + 4263936);        // N floats
    float* loss    = (float*)(ws + 4296704);        // N floats

    prep_k    <<<1 + (N * 16) / 256, 256, 0, stream>>>(q, y, qf8, counts, invy, pos, neg);
    gemm_k    <<<512, 256, 0, stream>>>(qf8, y, invy, pos, neg);
    finalize_k<<<N / 4, 256, 0, stream>>>(q, kmat, y, counts, pos, neg, loss);
    reduce_k  <<<1, 1024, 0, stream>>>(loss, out);
}